// Round 2
// baseline (816.413 us; speedup 1.0000x reference)
//
#include <hip/hip_runtime.h>
#include <math.h>

#define CH 64

__device__ __forceinline__ float wave_sum64(float v) {
#pragma unroll
  for (int off = 32; off > 0; off >>= 1) v += __shfl_xor(v, off, 64);
  return v;
}

__device__ __forceinline__ void wave_sum64_x4(float& a, float& b, float& c, float& d) {
#pragma unroll
  for (int off = 32; off > 0; off >>= 1) {
    a += __shfl_xor(a, off, 64);
    b += __shfl_xor(b, off, 64);
    c += __shfl_xor(c, off, 64);
    d += __shfl_xor(d, off, 64);
  }
}

// ---- CSR build ----------------------------------------------------------

__global__ void k_count(const int* __restrict__ dst, const float* __restrict__ w, int E,
                        int* __restrict__ cnt, float* __restrict__ wsum) {
  int i = blockIdx.x * blockDim.x + threadIdx.x;
  if (i < E) {
    int d = dst[i];
    atomicAdd(&cnt[d], 1);
    atomicAdd(&wsum[d], w[i]);
  }
}

__global__ void k_loopdeg(const int* __restrict__ cnt, const float* __restrict__ wsum,
                          float* __restrict__ loop_attr, int* __restrict__ deg, int n) {
  int i = blockIdx.x * blockDim.x + threadIdx.x;
  if (i < n) {
    int c = cnt[i];
    loop_attr[i] = wsum[i] / fmaxf((float)c, 1.0f);
    deg[i] = c + 1;  // +1 for self-loop
  }
}

// single-block exclusive scan over deg -> row_start[0..n]
__global__ void k_scan(const int* __restrict__ deg, int* __restrict__ row_start, int n) {
  __shared__ int swave[16];
  __shared__ int s_carry;
  int lane = threadIdx.x & 63;
  int wid = threadIdx.x >> 6;
  if (threadIdx.x == 0) s_carry = 0;
  __syncthreads();
  for (int base = 0; base < n; base += 1024) {
    int i = base + (int)threadIdx.x;
    int v = (i < n) ? deg[i] : 0;
    int x = v;
#pragma unroll
    for (int off = 1; off < 64; off <<= 1) {
      int t = __shfl_up(x, off, 64);
      if (lane >= off) x += t;
    }
    if (lane == 63) swave[wid] = x;
    __syncthreads();
    if (wid == 0) {
      int ws = (lane < 16) ? swave[lane] : 0;
#pragma unroll
      for (int off = 1; off < 16; off <<= 1) {
        int t = __shfl_up(ws, off, 64);
        if (lane >= off) ws += t;
      }
      if (lane < 16) swave[lane] = ws;  // inclusive scan of wave sums
    }
    __syncthreads();
    int waveoff = (wid == 0) ? 0 : swave[wid - 1];
    int carry = s_carry;
    int total = swave[15];
    __syncthreads();
    if (i < n) row_start[i] = carry + waveoff + x - v;  // exclusive
    if (threadIdx.x == 0) s_carry = carry + total;
    __syncthreads();
  }
  if (threadIdx.x == 0) row_start[n] = s_carry;
}

__global__ void k_scatter(const int* __restrict__ src, const int* __restrict__ dst,
                          const float* __restrict__ w, int E,
                          const int* __restrict__ row_start, int* __restrict__ cursor,
                          int2* __restrict__ csr) {
  int i = blockIdx.x * blockDim.x + threadIdx.x;
  if (i < E) {
    int d = dst[i];
    int pos = row_start[d] + atomicAdd(&cursor[d], 1);
    csr[pos] = make_int2(src[i], __float_as_int(w[i]));
  }
}

__global__ void k_selfloop(int n, const int* __restrict__ row_start, int* __restrict__ cursor,
                           int2* __restrict__ csr, const float* __restrict__ loop_attr) {
  int v = blockIdx.x * blockDim.x + threadIdx.x;
  if (v < n) {
    int pos = row_start[v] + atomicAdd(&cursor[v], 1);
    csr[pos] = make_int2(v, __float_as_int(loop_attr[v]));
  }
}

// ---- per-layer kernels --------------------------------------------------

// xl = x@Wl + bl ; xr = x@Wr + br   (one wave per row, lane = out channel)
__global__ void __launch_bounds__(256) k_transform(
    const float* __restrict__ x, const float* __restrict__ Wl, const float* __restrict__ bl,
    const float* __restrict__ Wr, const float* __restrict__ br,
    float* __restrict__ xl, float* __restrict__ xr, int n) {
  __shared__ float sW[2][CH * CH];  // 32 KB
  for (int i = threadIdx.x; i < CH * CH; i += blockDim.x) {
    sW[0][i] = Wl[i];
    sW[1][i] = Wr[i];
  }
  __syncthreads();
  int lane = threadIdx.x & 63;
  int wid = threadIdx.x >> 6;
  float blc = bl[lane], brc = br[lane];
  int wavesPerGrid = (gridDim.x * blockDim.x) >> 6;
  for (int row = blockIdx.x * (blockDim.x >> 6) + wid; row < n; row += wavesPerGrid) {
    float xv = x[(size_t)row * CH + lane];
    float accl = blc, accr = brc;
#pragma unroll
    for (int k = 0; k < CH; ++k) {
      float xk = __shfl(xv, k, 64);
      accl = fmaf(xk, sW[0][k * CH + lane], accl);
      accr = fmaf(xk, sW[1][k * CH + lane], accr);
    }
    xl[(size_t)row * CH + lane] = accl;
    xr[(size_t)row * CH + lane] = accr;
  }
}

// one wave per node: online-softmax attention aggregation over in-edges.
// Edge metadata prefetched one-per-lane per 64-edge chunk; edges processed in
// batches of 4 with interleaved butterfly reductions and a single rescale.
__global__ void __launch_bounds__(256) k_aggregate(
    const float* __restrict__ xl, const float* __restrict__ xr,
    const int* __restrict__ row_start, const int2* __restrict__ csr,
    const float* __restrict__ We, const float* __restrict__ att, const float* __restrict__ bo,
    float* __restrict__ out, int n) {
  int lane = threadIdx.x & 63;
  int v = (blockIdx.x * blockDim.x + threadIdx.x) >> 6;
  if (v >= n) return;
  float Wec = We[lane], attc = att[lane], boc = bo[lane];
  float xrc = xr[(size_t)v * CH + lane];
  int beg = row_start[v], end = row_start[v + 1];
  float m = -INFINITY, s = 0.f, acc = 0.f;
  for (int chunk = beg; chunk < end; chunk += 64) {
    int nc = min(64, end - chunk);
    int2 ed = (lane < nc) ? csr[chunk + lane] : make_int2(0, 0);
    int e = 0;
    for (; e + 4 <= nc; e += 4) {
      int s0 = __shfl(ed.x, e, 64);
      int s1 = __shfl(ed.x, e + 1, 64);
      int s2 = __shfl(ed.x, e + 2, 64);
      int s3 = __shfl(ed.x, e + 3, 64);
      float a0 = __int_as_float(__shfl(ed.y, e, 64));
      float a1 = __int_as_float(__shfl(ed.y, e + 1, 64));
      float a2 = __int_as_float(__shfl(ed.y, e + 2, 64));
      float a3 = __int_as_float(__shfl(ed.y, e + 3, 64));
      float x0 = xl[(size_t)s0 * CH + lane];
      float x1 = xl[(size_t)s1 * CH + lane];
      float x2 = xl[(size_t)s2 * CH + lane];
      float x3 = xl[(size_t)s3 * CH + lane];
      float e0 = fmaf(a0, Wec, x0 + xrc);
      float e1 = fmaf(a1, Wec, x1 + xrc);
      float e2 = fmaf(a2, Wec, x2 + xrc);
      float e3 = fmaf(a3, Wec, x3 + xrc);
      float l0 = (e0 > 0.f ? e0 : 0.2f * e0) * attc;
      float l1 = (e1 > 0.f ? e1 : 0.2f * e1) * attc;
      float l2 = (e2 > 0.f ? e2 : 0.2f * e2) * attc;
      float l3 = (e3 > 0.f ? e3 : 0.2f * e3) * attc;
      wave_sum64_x4(l0, l1, l2, l3);
      float bm = fmaxf(fmaxf(l0, l1), fmaxf(l2, l3));
      float mn = fmaxf(m, bm);
      float sc = expf(m - mn);  // first batch: expf(-inf)=0
      float p0 = expf(l0 - mn);
      float p1 = expf(l1 - mn);
      float p2 = expf(l2 - mn);
      float p3 = expf(l3 - mn);
      s = fmaf(s, sc, (p0 + p1) + (p2 + p3));
      float dot = fmaf(p0, x0, fmaf(p1, x1, fmaf(p2, x2, p3 * x3)));
      acc = fmaf(acc, sc, dot);
      m = mn;
    }
    for (; e < nc; ++e) {
      int s0 = __shfl(ed.x, e, 64);
      float a0 = __int_as_float(__shfl(ed.y, e, 64));
      float x0 = xl[(size_t)s0 * CH + lane];
      float e0 = fmaf(a0, Wec, x0 + xrc);
      float lr = (e0 > 0.f ? e0 : 0.2f * e0) * attc;
      float logit = wave_sum64(lr);
      float mn = fmaxf(m, logit);
      float sc = expf(m - mn);
      float p = expf(logit - mn);
      s = fmaf(s, sc, p);
      acc = fmaf(acc, sc, p * x0);
      m = mn;
    }
  }
  out[(size_t)v * CH + lane] = acc / s + boc;
}

// last layer: C_out = 1. xl8[v] = x[v,:]@Wl8 + bl8 (wave per node)
__global__ void __launch_bounds__(256) k_transform8(
    const float* __restrict__ x, const float* __restrict__ Wl, const float* __restrict__ bl,
    const float* __restrict__ Wr, const float* __restrict__ br,
    float* __restrict__ xl8, float* __restrict__ xr8, int n) {
  int lane = threadIdx.x & 63;
  int v = (blockIdx.x * blockDim.x + threadIdx.x) >> 6;
  if (v >= n) return;
  float xv = x[(size_t)v * CH + lane];
  float a = xv * Wl[lane];
  float b = xv * Wr[lane];
#pragma unroll
  for (int off = 32; off > 0; off >>= 1) {
    a += __shfl_xor(a, off, 64);
    b += __shfl_xor(b, off, 64);
  }
  if (lane == 0) {
    xl8[v] = a + bl[0];
    xr8[v] = b + br[0];
  }
}

// last layer aggregation (scalar channel) fused with mean pool -> out[0]
__global__ void __launch_bounds__(256) k_agg8mean(
    const float* __restrict__ xl8, const float* __restrict__ xr8,
    const int* __restrict__ row_start, const int2* __restrict__ csr,
    const float* __restrict__ We, const float* __restrict__ att, const float* __restrict__ bo,
    float* __restrict__ out, int n) {
  int v = blockIdx.x * blockDim.x + threadIdx.x;
  float val = 0.f;
  if (v < n) {
    float xrc = xr8[v];
    float We0 = We[0], att0 = att[0];
    float m = -INFINITY, s = 0.f, acc = 0.f;
    int beg = row_start[v], end = row_start[v + 1];
    for (int i = beg; i < end; ++i) {
      int2 ed = csr[i];
      float xlc = xl8[ed.x];
      float e = fmaf(__int_as_float(ed.y), We0, xlc + xrc);
      float logit = (e > 0.f ? e : 0.2f * e) * att0;
      float mn = fmaxf(m, logit);
      float sc = expf(m - mn);
      float p = expf(logit - mn);
      s = fmaf(s, sc, p);
      acc = fmaf(acc, sc, p * xlc);
      m = mn;
    }
    val = acc / s + bo[0];
  }
  val = wave_sum64(val);
  __shared__ float swave[4];
  int lane = threadIdx.x & 63, wid = threadIdx.x >> 6;
  if (lane == 0) swave[wid] = val;
  __syncthreads();
  if (threadIdx.x == 0) {
    float t = swave[0] + swave[1] + swave[2] + swave[3];
    atomicAdd(out, t / (float)n);
  }
}

// ---- host ---------------------------------------------------------------

extern "C" void kernel_launch(void* const* d_in, const int* in_sizes, int n_in,
                              void* d_out, int out_size, void* d_ws, size_t ws_size,
                              hipStream_t stream) {
  const float* features = (const float*)d_in[0];
  const int* edge_src = (const int*)d_in[1];
  const int* edge_dst = (const int*)d_in[2];
  const float* edge_w = (const float*)d_in[3];
  const int N = in_sizes[0] / CH;
  const int E = in_sizes[1];

  char* p = (char*)d_ws;
  auto take = [&](size_t bytes) {
    char* r = p;
    p += (bytes + 255) & ~(size_t)255;
    return r;
  };
  float* xbuf0 = (float*)take((size_t)N * CH * 4);
  float* xbuf1 = (float*)take((size_t)N * CH * 4);
  float* xl = (float*)take((size_t)N * CH * 4);
  float* xr = (float*)take((size_t)N * CH * 4);
  int2* csr = (int2*)take((size_t)(E + N) * 8);
  char* zero_region = take((size_t)N * 4 * 3);
  int* cnt = (int*)zero_region;
  float* wsum = (float*)(zero_region + (size_t)N * 4);
  int* cursor = (int*)(zero_region + (size_t)N * 8);
  float* loop_attr = (float*)take((size_t)N * 4);
  int* deg = (int*)take((size_t)N * 4);
  int* row_start = (int*)take(((size_t)N + 1) * 4);
  float* xl8 = (float*)take((size_t)N * 4);
  float* xr8 = (float*)take((size_t)N * 4);

  hipMemsetAsync(zero_region, 0, (size_t)N * 4 * 3, stream);
  hipMemsetAsync(d_out, 0, sizeof(float), stream);

  const int tb = 256;
  k_count<<<(E + tb - 1) / tb, tb, 0, stream>>>(edge_dst, edge_w, E, cnt, wsum);
  k_loopdeg<<<(N + tb - 1) / tb, tb, 0, stream>>>(cnt, wsum, loop_attr, deg, N);
  k_scan<<<1, 1024, 0, stream>>>(deg, row_start, N);
  k_scatter<<<(E + tb - 1) / tb, tb, 0, stream>>>(edge_src, edge_dst, edge_w, E, row_start,
                                                  cursor, csr);
  k_selfloop<<<(N + tb - 1) / tb, tb, 0, stream>>>(N, row_start, cursor, csr, loop_attr);

  const float* x = features;
  float* ping = xbuf0;
  float* pong = xbuf1;
  for (int layer = 0; layer < 7; ++layer) {
    const float *Wl, *bl, *Wr, *br, *We, *att, *bo;
    if (layer == 0) {
      Wl = (const float*)d_in[4];  bl = (const float*)d_in[5];
      Wr = (const float*)d_in[6];  br = (const float*)d_in[7];
      We = (const float*)d_in[8];  att = (const float*)d_in[9];
      bo = (const float*)d_in[10];
    } else {
      int i = layer - 1;
      Wl = (const float*)d_in[11] + (size_t)i * CH * CH;
      bl = (const float*)d_in[12] + (size_t)i * CH;
      Wr = (const float*)d_in[13] + (size_t)i * CH * CH;
      br = (const float*)d_in[14] + (size_t)i * CH;
      We = (const float*)d_in[15] + (size_t)i * CH;
      att = (const float*)d_in[16] + (size_t)i * CH;
      bo = (const float*)d_in[17] + (size_t)i * CH;
    }
    k_transform<<<1024, 256, 0, stream>>>(x, Wl, bl, Wr, br, xl, xr, N);
    k_aggregate<<<((size_t)N * 64 + tb - 1) / tb, tb, 0, stream>>>(
        xl, xr, row_start, csr, We, att, bo, ping, N);
    x = ping;
    float* t = ping; ping = pong; pong = t;
  }
  k_transform8<<<((size_t)N * 64 + tb - 1) / tb, tb, 0, stream>>>(
      x, (const float*)d_in[18], (const float*)d_in[19], (const float*)d_in[20],
      (const float*)d_in[21], xl8, xr8, N);
  k_agg8mean<<<(N + tb - 1) / tb, tb, 0, stream>>>(
      xl8, xr8, row_start, csr, (const float*)d_in[22], (const float*)d_in[23],
      (const float*)d_in[24], (float*)d_out, N);
}

// Round 5
// 795.412 us; speedup vs baseline: 1.0264x; 1.0264x over previous
//
#include <hip/hip_runtime.h>
#include <math.h>

#define CH 64

// ---- multi-value wave reduction ----------------------------------------
// Sums 8 per-lane values over all 64 lanes; returns all 8 totals in L[0..7]
// in every lane. Merge-tree: 18 shuffles instead of 48.
// After the 3 merge stages lane l owns value j=(l>>3)&7; broadcast from 8j.
__device__ __forceinline__ void multi_reduce8(const float lv[8], float L[8], int lane) {
  bool b5 = (lane & 32) != 0;
  float r1[4];
#pragma unroll
  for (int j = 0; j < 4; ++j) {
    float keep = b5 ? lv[j + 4] : lv[j];
    float send = b5 ? lv[j] : lv[j + 4];
    r1[j] = keep + __shfl_xor(send, 32, 64);
  }
  bool b4 = (lane & 16) != 0;
  float r2[2];
#pragma unroll
  for (int j = 0; j < 2; ++j) {
    float keep = b4 ? r1[j + 2] : r1[j];
    float send = b4 ? r1[j] : r1[j + 2];
    r2[j] = keep + __shfl_xor(send, 16, 64);
  }
  bool b3 = (lane & 8) != 0;
  float keep = b3 ? r2[1] : r2[0];
  float send = b3 ? r2[0] : r2[1];
  float v = keep + __shfl_xor(send, 8, 64);
  v += __shfl_xor(v, 4, 64);
  v += __shfl_xor(v, 2, 64);
  v += __shfl_xor(v, 1, 64);
#pragma unroll
  for (int j = 0; j < 8; ++j) L[j] = __shfl(v, j * 8, 64);
}

// ---- CSR build ----------------------------------------------------------

__global__ void k_count(const int* __restrict__ dst, const float* __restrict__ w, int E,
                        int* __restrict__ cnt, float* __restrict__ wsum) {
  int i = blockIdx.x * blockDim.x + threadIdx.x;
  if (i < E) {
    int d = dst[i];
    atomicAdd(&cnt[d], 1);
    atomicAdd(&wsum[d], w[i]);
  }
}

// per-node: loop_attr, deg, row_beg via wave-aggregated atomic allocation
// (CSR rows need not be in node order - disjoint is enough)
__global__ void k_alloc(const int* __restrict__ cnt, const float* __restrict__ wsum,
                        float* __restrict__ loop_attr, int* __restrict__ deg,
                        int* __restrict__ row_beg, int* __restrict__ total, int n) {
  int i = blockIdx.x * blockDim.x + threadIdx.x;
  int lane = threadIdx.x & 63;
  int d = 0;
  if (i < n) {
    int c = cnt[i];
    loop_attr[i] = wsum[i] / fmaxf((float)c, 1.0f);
    d = c + 1;  // +1 self-loop
    deg[i] = d;
  }
  int x = d;
#pragma unroll
  for (int off = 1; off < 64; off <<= 1) {
    int t = __shfl_up(x, off, 64);
    if (lane >= off) x += t;
  }
  int base = 0;
  if (lane == 63) base = atomicAdd(total, x);
  base = __shfl(base, 63, 64);
  if (i < n) row_beg[i] = base + x - d;  // exclusive within wave
}

__global__ void k_scatter(const int* __restrict__ src, const int* __restrict__ dst,
                          const float* __restrict__ w, int E,
                          const int* __restrict__ row_beg, int* __restrict__ cursor,
                          int2* __restrict__ csr) {
  int i = blockIdx.x * blockDim.x + threadIdx.x;
  if (i < E) {
    int d = dst[i];
    int pos = row_beg[d] + atomicAdd(&cursor[d], 1);
    csr[pos] = make_int2(src[i], __float_as_int(w[i]));
  }
}

__global__ void k_selfloop(int n, const int* __restrict__ row_beg, int* __restrict__ cursor,
                           int2* __restrict__ csr, const float* __restrict__ loop_attr) {
  int v = blockIdx.x * blockDim.x + threadIdx.x;
  if (v < n) {
    int pos = row_beg[v] + atomicAdd(&cursor[v], 1);
    csr[pos] = make_int2(v, __float_as_int(loop_attr[v]));
  }
}

// ---- layer-1 transform (standalone) -------------------------------------

__global__ void __launch_bounds__(256) k_transform(
    const float* __restrict__ x, const float* __restrict__ Wl, const float* __restrict__ bl,
    const float* __restrict__ Wr, const float* __restrict__ br,
    float* __restrict__ xl, float* __restrict__ xr, int n) {
  __shared__ float sW[2][CH * CH];  // 32 KB
  for (int i = threadIdx.x; i < (CH * CH) / 4; i += blockDim.x) {
    ((float4*)sW[0])[i] = ((const float4*)Wl)[i];
    ((float4*)sW[1])[i] = ((const float4*)Wr)[i];
  }
  __syncthreads();
  int lane = threadIdx.x & 63;
  int wid = threadIdx.x >> 6;
  float blc = bl[lane], brc = br[lane];
  int wavesPerGrid = (gridDim.x * blockDim.x) >> 6;
  for (int row = blockIdx.x * (blockDim.x >> 6) + wid; row < n; row += wavesPerGrid) {
    float xv = x[(size_t)row * CH + lane];
    float accl = blc, accr = brc;
#pragma unroll
    for (int k = 0; k < CH; ++k) {
      float xk = __shfl(xv, k, 64);
      accl = fmaf(xk, sW[0][k * CH + lane], accl);
      accr = fmaf(xk, sW[1][k * CH + lane], accr);
    }
    xl[(size_t)row * CH + lane] = accl;
    xr[(size_t)row * CH + lane] = accr;
  }
}

// ---- fused aggregate(layer i) + transform(layer i+1) ---------------------
// wave per node; lane = channel. 8-edge batches, gathers issued up-front,
// merge-tree logit reduction, masked tail, one fast-exp rescale per batch.
// Output row stays in registers and feeds the next layer's 64x64 transform.

__global__ void __launch_bounds__(256) k_agg_tr(
    const float* __restrict__ xl, const float* __restrict__ xr,
    const int* __restrict__ row_beg, const int* __restrict__ deg,
    const int2* __restrict__ csr,
    const float* __restrict__ We, const float* __restrict__ att, const float* __restrict__ bo,
    const float* __restrict__ Wl2, const float* __restrict__ bl2,
    const float* __restrict__ Wr2, const float* __restrict__ br2,
    float* __restrict__ xl2, float* __restrict__ xr2, int n) {
  __shared__ float sWl[CH * CH], sWr[CH * CH];  // 32 KB
  for (int i = threadIdx.x; i < (CH * CH) / 4; i += blockDim.x) {
    ((float4*)sWl)[i] = ((const float4*)Wl2)[i];
    ((float4*)sWr)[i] = ((const float4*)Wr2)[i];
  }
  __syncthreads();
  int lane = threadIdx.x & 63;
  int wid = threadIdx.x >> 6;
  float Wec = We[lane], attc = att[lane], boc = bo[lane];
  float blc = bl2[lane], brc = br2[lane];
  int nwaves = gridDim.x * 4;
  for (int v = blockIdx.x * 4 + wid; v < n; v += nwaves) {
    float xrc = xr[(size_t)v * CH + lane];
    int beg = row_beg[v], dv = deg[v];
    float m = -INFINITY, s = 0.f, acc = 0.f;
    for (int chunk = 0; chunk < dv; chunk += 64) {
      int nc = min(64, dv - chunk);
      int2 ed = (lane < nc) ? csr[beg + chunk + lane] : make_int2(0, 0);
      for (int e = 0; e < nc; e += 8) {
        float xv[8], lv[8], L[8];
#pragma unroll
        for (int j = 0; j < 8; ++j) {
          int sj = __shfl(ed.x, e + j, 64);
          xv[j] = xl[(size_t)sj * CH + lane];  // 8 independent gathers in flight
        }
#pragma unroll
        for (int j = 0; j < 8; ++j) {
          float aj = __int_as_float(__shfl(ed.y, e + j, 64));
          float ee = fmaf(aj, Wec, xv[j] + xrc);
          lv[j] = (ee > 0.f ? ee : 0.2f * ee) * attc;
        }
        multi_reduce8(lv, L, lane);
#pragma unroll
        for (int j = 0; j < 8; ++j)
          if (e + j >= nc) L[j] = -INFINITY;  // masked tail
        float bm = fmaxf(fmaxf(fmaxf(L[0], L[1]), fmaxf(L[2], L[3])),
                         fmaxf(fmaxf(L[4], L[5]), fmaxf(L[6], L[7])));
        float mn = fmaxf(m, bm);
        float sc = __expf(m - mn);  // first batch: exp(-inf)=0
        float psum = 0.f, pdot = 0.f;
#pragma unroll
        for (int j = 0; j < 8; ++j) {
          float p = __expf(L[j] - mn);
          psum += p;
          pdot = fmaf(p, xv[j], pdot);
        }
        s = fmaf(s, sc, psum);
        acc = fmaf(acc, sc, pdot);
        m = mn;
      }
    }
    float orow = acc / s + boc;  // this layer's output row (lane = channel)
    // fused next-layer transform
    float accl = blc, accr = brc;
#pragma unroll
    for (int k = 0; k < CH; ++k) {
      float xk = __shfl(orow, k, 64);
      accl = fmaf(xk, sWl[k * CH + lane], accl);
      accr = fmaf(xk, sWr[k * CH + lane], accr);
    }
    xl2[(size_t)v * CH + lane] = accl;
    xr2[(size_t)v * CH + lane] = accr;
  }
}

// fused aggregate(layer 7) + transform(layer 8, 64->1)
__global__ void __launch_bounds__(256) k_agg_tr8(
    const float* __restrict__ xl, const float* __restrict__ xr,
    const int* __restrict__ row_beg, const int* __restrict__ deg,
    const int2* __restrict__ csr,
    const float* __restrict__ We, const float* __restrict__ att, const float* __restrict__ bo,
    const float* __restrict__ Wl8, const float* __restrict__ bl8,
    const float* __restrict__ Wr8, const float* __restrict__ br8,
    float* __restrict__ xl8, float* __restrict__ xr8, int n) {
  int lane = threadIdx.x & 63;
  int wid = threadIdx.x >> 6;
  float Wec = We[lane], attc = att[lane], boc = bo[lane];
  float wl8c = Wl8[lane], wr8c = Wr8[lane];
  float bl80 = bl8[0], br80 = br8[0];
  int nwaves = gridDim.x * 4;
  for (int v = blockIdx.x * 4 + wid; v < n; v += nwaves) {
    float xrc = xr[(size_t)v * CH + lane];
    int beg = row_beg[v], dv = deg[v];
    float m = -INFINITY, s = 0.f, acc = 0.f;
    for (int chunk = 0; chunk < dv; chunk += 64) {
      int nc = min(64, dv - chunk);
      int2 ed = (lane < nc) ? csr[beg + chunk + lane] : make_int2(0, 0);
      for (int e = 0; e < nc; e += 8) {
        float xv[8], lv[8], L[8];
#pragma unroll
        for (int j = 0; j < 8; ++j) {
          int sj = __shfl(ed.x, e + j, 64);
          xv[j] = xl[(size_t)sj * CH + lane];
        }
#pragma unroll
        for (int j = 0; j < 8; ++j) {
          float aj = __int_as_float(__shfl(ed.y, e + j, 64));
          float ee = fmaf(aj, Wec, xv[j] + xrc);
          lv[j] = (ee > 0.f ? ee : 0.2f * ee) * attc;
        }
        multi_reduce8(lv, L, lane);
#pragma unroll
        for (int j = 0; j < 8; ++j)
          if (e + j >= nc) L[j] = -INFINITY;
        float bm = fmaxf(fmaxf(fmaxf(L[0], L[1]), fmaxf(L[2], L[3])),
                         fmaxf(fmaxf(L[4], L[5]), fmaxf(L[6], L[7])));
        float mn = fmaxf(m, bm);
        float sc = __expf(m - mn);
        float psum = 0.f, pdot = 0.f;
#pragma unroll
        for (int j = 0; j < 8; ++j) {
          float p = __expf(L[j] - mn);
          psum += p;
          pdot = fmaf(p, xv[j], pdot);
        }
        s = fmaf(s, sc, psum);
        acc = fmaf(acc, sc, pdot);
        m = mn;
      }
    }
    float orow = acc / s + boc;
    float a = orow * wl8c;
    float b = orow * wr8c;
#pragma unroll
    for (int off = 32; off > 0; off >>= 1) {
      a += __shfl_xor(a, off, 64);
      b += __shfl_xor(b, off, 64);
    }
    if (lane == 0) {
      xl8[v] = a + bl80;
      xr8[v] = b + br80;
    }
  }
}

// last layer aggregation (scalar channel), lane-per-edge, fused mean pool
__global__ void __launch_bounds__(256) k_agg8_mean(
    const float* __restrict__ xl8, const float* __restrict__ xr8,
    const int* __restrict__ row_beg, const int* __restrict__ deg,
    const int2* __restrict__ csr,
    const float* __restrict__ We, const float* __restrict__ att, const float* __restrict__ bo,
    float* __restrict__ out, int n) {
  int lane = threadIdx.x & 63;
  int wid = threadIdx.x >> 6;
  float We0 = We[0], att0 = att[0], bo0 = bo[0];
  float inv_n = 1.0f / (float)n;
  float local = 0.f;
  int nwaves = gridDim.x * 4;
  for (int v = blockIdx.x * 4 + wid; v < n; v += nwaves) {
    float xrc = xr8[v];
    int beg = row_beg[v], dv = deg[v];
    float m = -INFINITY, s = 0.f, acc = 0.f;
    for (int chunk = 0; chunk < dv; chunk += 64) {
      int idx = chunk + lane;
      bool valid = idx < dv;
      int2 ed = valid ? csr[beg + idx] : make_int2(0, 0);
      float xlc = valid ? xl8[ed.x] : 0.f;
      float ee = fmaf(__int_as_float(ed.y), We0, xlc + xrc);
      float logit = valid ? (ee > 0.f ? ee : 0.2f * ee) * att0 : -INFINITY;
      float bm = logit;
#pragma unroll
      for (int off = 32; off > 0; off >>= 1) bm = fmaxf(bm, __shfl_xor(bm, off, 64));
      float mn = fmaxf(m, bm);
      float p = __expf(logit - mn);
      float pd = p * xlc;
#pragma unroll
      for (int off = 32; off > 0; off >>= 1) {
        p += __shfl_xor(p, off, 64);
        pd += __shfl_xor(pd, off, 64);
      }
      float sc = __expf(m - mn);
      s = fmaf(s, sc, p);
      acc = fmaf(acc, sc, pd);
      m = mn;
    }
    local += (acc / s + bo0) * inv_n;
  }
  __shared__ float sw[4];
  if (lane == 0) sw[wid] = local;
  __syncthreads();
  if (threadIdx.x == 0) atomicAdd(out, sw[0] + sw[1] + sw[2] + sw[3]);
}

// ---- host ---------------------------------------------------------------

extern "C" void kernel_launch(void* const* d_in, const int* in_sizes, int n_in,
                              void* d_out, int out_size, void* d_ws, size_t ws_size,
                              hipStream_t stream) {
  const float* features = (const float*)d_in[0];
  const int* edge_src = (const int*)d_in[1];
  const int* edge_dst = (const int*)d_in[2];
  const float* edge_w = (const float*)d_in[3];
  const int N = in_sizes[0] / CH;
  const int E = in_sizes[1];

  char* p = (char*)d_ws;
  auto take = [&](size_t bytes) {
    char* r = p;
    p += (bytes + 255) & ~(size_t)255;
    return r;
  };
  float* xlA = (float*)take((size_t)N * CH * 4);
  float* xrA = (float*)take((size_t)N * CH * 4);
  float* xlB = (float*)take((size_t)N * CH * 4);
  float* xrB = (float*)take((size_t)N * CH * 4);
  int2* csr = (int2*)take((size_t)(E + N) * 8);
  char* zero_region = take((size_t)N * 4 * 3 + 256);
  int* cnt = (int*)zero_region;
  float* wsum = (float*)(zero_region + (size_t)N * 4);
  int* cursor = (int*)(zero_region + (size_t)N * 8);
  int* total = (int*)(zero_region + (size_t)N * 12);
  float* loop_attr = (float*)take((size_t)N * 4);
  int* deg = (int*)take((size_t)N * 4);
  int* row_beg = (int*)take((size_t)N * 4);
  float* xl8 = (float*)take((size_t)N * 4);
  float* xr8 = (float*)take((size_t)N * 4);

  hipMemsetAsync(zero_region, 0, (size_t)N * 4 * 3 + 256, stream);
  hipMemsetAsync(d_out, 0, sizeof(float), stream);

  const int tb = 256;
  k_count<<<(E + tb - 1) / tb, tb, 0, stream>>>(edge_dst, edge_w, E, cnt, wsum);
  k_alloc<<<(N + tb - 1) / tb, tb, 0, stream>>>(cnt, wsum, loop_attr, deg, row_beg, total, N);
  k_scatter<<<(E + tb - 1) / tb, tb, 0, stream>>>(edge_src, edge_dst, edge_w, E, row_beg,
                                                  cursor, csr);
  k_selfloop<<<(N + tb - 1) / tb, tb, 0, stream>>>(N, row_beg, cursor, csr, loop_attr);

  // param pointers
  const float* Wl1 = (const float*)d_in[4];
  const float* bl1 = (const float*)d_in[5];
  const float* Wr1 = (const float*)d_in[6];
  const float* br1 = (const float*)d_in[7];
  const float* We1 = (const float*)d_in[8];
  const float* att1 = (const float*)d_in[9];
  const float* bo1 = (const float*)d_in[10];
  const float* Wlm = (const float*)d_in[11];
  const float* blm = (const float*)d_in[12];
  const float* Wrm = (const float*)d_in[13];
  const float* brm = (const float*)d_in[14];
  const float* Wem = (const float*)d_in[15];
  const float* attm = (const float*)d_in[16];
  const float* bom = (const float*)d_in[17];

  // T1: features -> xlA/xrA
  k_transform<<<1024, 256, 0, stream>>>(features, Wl1, bl1, Wr1, br1, xlA, xrA, N);

  const int AG_BLOCKS = 2048;
  float* xl_cur = xlA;
  float* xr_cur = xrA;
  float* xl_nxt = xlB;
  float* xr_nxt = xrB;
  // F1..F6: aggregate layer i (i=1..6) + transform layer i+1
  for (int i = 0; i < 6; ++i) {
    const float *We, *att, *bo;
    if (i == 0) {
      We = We1; att = att1; bo = bo1;
    } else {
      We = Wem + (size_t)(i - 1) * CH;
      att = attm + (size_t)(i - 1) * CH;
      bo = bom + (size_t)(i - 1) * CH;
    }
    const float* Wl2 = Wlm + (size_t)i * CH * CH;
    const float* bl2 = blm + (size_t)i * CH;
    const float* Wr2 = Wrm + (size_t)i * CH * CH;
    const float* br2 = brm + (size_t)i * CH;
    k_agg_tr<<<AG_BLOCKS, 256, 0, stream>>>(xl_cur, xr_cur, row_beg, deg, csr, We, att, bo,
                                            Wl2, bl2, Wr2, br2, xl_nxt, xr_nxt, N);
    float* t;
    t = xl_cur; xl_cur = xl_nxt; xl_nxt = t;
    t = xr_cur; xr_cur = xr_nxt; xr_nxt = t;
  }
  // F7: aggregate layer 7 (mid idx 5) + transform layer 8 (64->1)
  k_agg_tr8<<<AG_BLOCKS, 256, 0, stream>>>(
      xl_cur, xr_cur, row_beg, deg, csr, Wem + (size_t)5 * CH, attm + (size_t)5 * CH,
      bom + (size_t)5 * CH, (const float*)d_in[18], (const float*)d_in[19],
      (const float*)d_in[20], (const float*)d_in[21], xl8, xr8, N);
  // A8 + mean pool
  k_agg8_mean<<<1024, 256, 0, stream>>>(xl8, xr8, row_beg, deg, csr, (const float*)d_in[22],
                                        (const float*)d_in[23], (const float*)d_in[24],
                                        (float*)d_out, N);
}

// Round 6
// 655.050 us; speedup vs baseline: 1.2463x; 1.2143x over previous
//
#include <hip/hip_runtime.h>
#include <math.h>

#define CH 64

// ---- multi-value wave reduction ----------------------------------------
// Sums 8 per-lane values over all 64 lanes; returns all 8 totals in L[0..7]
// in every lane. Merge-tree: 18 shuffles instead of 48. After the 3 merge
// stages lane l owns value j=(l>>3)&7; broadcast from lane 8j.
__device__ __forceinline__ void multi_reduce8(const float lv[8], float L[8], int lane) {
  bool b5 = (lane & 32) != 0;
  float r1[4];
#pragma unroll
  for (int j = 0; j < 4; ++j) {
    float keep = b5 ? lv[j + 4] : lv[j];
    float send = b5 ? lv[j] : lv[j + 4];
    r1[j] = keep + __shfl_xor(send, 32, 64);
  }
  bool b4 = (lane & 16) != 0;
  float r2[2];
#pragma unroll
  for (int j = 0; j < 2; ++j) {
    float keep = b4 ? r1[j + 2] : r1[j];
    float send = b4 ? r1[j] : r1[j + 2];
    r2[j] = keep + __shfl_xor(send, 16, 64);
  }
  bool b3 = (lane & 8) != 0;
  float keep = b3 ? r2[1] : r2[0];
  float send = b3 ? r2[0] : r2[1];
  float v = keep + __shfl_xor(send, 8, 64);
  v += __shfl_xor(v, 4, 64);
  v += __shfl_xor(v, 2, 64);
  v += __shfl_xor(v, 1, 64);
#pragma unroll
  for (int j = 0; j < 8; ++j) L[j] = __shfl(v, j * 8, 64);
}

// ---- CSR build ----------------------------------------------------------

__global__ void k_count(const int* __restrict__ dst, const float* __restrict__ w, int E,
                        int* __restrict__ cnt, float* __restrict__ wsum) {
  int i = blockIdx.x * blockDim.x + threadIdx.x;
  if (i < E) {
    int d = dst[i];
    atomicAdd(&cnt[d], 1);
    atomicAdd(&wsum[d], w[i]);
  }
}

// per-node: loop_attr, deg, row_beg via wave-aggregated atomic allocation
__global__ void k_alloc(const int* __restrict__ cnt, const float* __restrict__ wsum,
                        float* __restrict__ loop_attr, int* __restrict__ deg,
                        int* __restrict__ row_beg, int* __restrict__ total, int n) {
  int i = blockIdx.x * blockDim.x + threadIdx.x;
  int lane = threadIdx.x & 63;
  int d = 0;
  if (i < n) {
    int c = cnt[i];
    loop_attr[i] = wsum[i] / fmaxf((float)c, 1.0f);
    d = c + 1;  // +1 self-loop
    deg[i] = d;
  }
  int x = d;
#pragma unroll
  for (int off = 1; off < 64; off <<= 1) {
    int t = __shfl_up(x, off, 64);
    if (lane >= off) x += t;
  }
  int base = 0;
  if (lane == 63) base = atomicAdd(total, x);
  base = __shfl(base, 63, 64);
  if (i < n) row_beg[i] = base + x - d;  // exclusive within wave
}

__global__ void k_scatter(const int* __restrict__ src, const int* __restrict__ dst,
                          const float* __restrict__ w, int E,
                          const int* __restrict__ row_beg, int* __restrict__ cursor,
                          int2* __restrict__ csr) {
  int i = blockIdx.x * blockDim.x + threadIdx.x;
  if (i < E) {
    int d = dst[i];
    int pos = row_beg[d] + atomicAdd(&cursor[d], 1);
    csr[pos] = make_int2(src[i], __float_as_int(w[i]));
  }
}

__global__ void k_selfloop(int n, const int* __restrict__ row_beg, int* __restrict__ cursor,
                           int2* __restrict__ csr, const float* __restrict__ loop_attr) {
  int v = blockIdx.x * blockDim.x + threadIdx.x;
  if (v < n) {
    int pos = row_beg[v] + atomicAdd(&cursor[v], 1);
    csr[pos] = make_int2(v, __float_as_int(loop_attr[v]));
  }
}

// ---- transform: xl = x@Wl + bl ; xr = x@Wr + br (wave/row, lane=out ch) --

__global__ void __launch_bounds__(256) k_transform(
    const float* __restrict__ x, const float* __restrict__ Wl, const float* __restrict__ bl,
    const float* __restrict__ Wr, const float* __restrict__ br,
    float* __restrict__ xl, float* __restrict__ xr, int n) {
  __shared__ float sW[2][CH * CH];  // 32 KB
  for (int i = threadIdx.x; i < (CH * CH) / 4; i += blockDim.x) {
    ((float4*)sW[0])[i] = ((const float4*)Wl)[i];
    ((float4*)sW[1])[i] = ((const float4*)Wr)[i];
  }
  __syncthreads();
  int lane = threadIdx.x & 63;
  int wid = threadIdx.x >> 6;
  float blc = bl[lane], brc = br[lane];
  int wavesPerGrid = (gridDim.x * blockDim.x) >> 6;
  for (int row = blockIdx.x * (blockDim.x >> 6) + wid; row < n; row += wavesPerGrid) {
    float xv = x[(size_t)row * CH + lane];
    float accl = blc, accr = brc;
#pragma unroll
    for (int k = 0; k < CH; ++k) {
      float xk = __shfl(xv, k, 64);
      accl = fmaf(xk, sW[0][k * CH + lane], accl);
      accr = fmaf(xk, sW[1][k * CH + lane], accr);
    }
    xl[(size_t)row * CH + lane] = accl;
    xr[(size_t)row * CH + lane] = accr;
  }
}

// ---- aggregate: one wave per node, online softmax over in-edges ----------
// 8-edge batches, 8 gathers in flight, merge-tree logit reduction, fast exp.
// Lean register footprint: no LDS, direct node index, no fused transform.

__global__ void __launch_bounds__(256) k_aggregate(
    const float* __restrict__ xl, const float* __restrict__ xr,
    const int* __restrict__ row_beg, const int* __restrict__ deg,
    const int2* __restrict__ csr,
    const float* __restrict__ We, const float* __restrict__ att, const float* __restrict__ bo,
    float* __restrict__ out, int n) {
  int lane = threadIdx.x & 63;
  int v = (blockIdx.x * blockDim.x + threadIdx.x) >> 6;
  if (v >= n) return;
  float Wec = We[lane], attc = att[lane], boc = bo[lane];
  float xrc = xr[(size_t)v * CH + lane];
  int beg = row_beg[v], dv = deg[v];
  float m = -INFINITY, s = 0.f, acc = 0.f;
  for (int chunk = 0; chunk < dv; chunk += 64) {
    int nc = min(64, dv - chunk);
    int2 ed = (lane < nc) ? csr[beg + chunk + lane] : make_int2(0, 0);
    for (int e = 0; e < nc; e += 8) {
      float xv[8], lv[8], L[8];
#pragma unroll
      for (int j = 0; j < 8; ++j) {
        int sj = __shfl(ed.x, e + j, 64);
        xv[j] = xl[(size_t)sj * CH + lane];  // 8 independent gathers in flight
      }
#pragma unroll
      for (int j = 0; j < 8; ++j) {
        float aj = __int_as_float(__shfl(ed.y, e + j, 64));
        float ee = fmaf(aj, Wec, xv[j] + xrc);
        lv[j] = (ee > 0.f ? ee : 0.2f * ee) * attc;
      }
      multi_reduce8(lv, L, lane);
#pragma unroll
      for (int j = 0; j < 8; ++j)
        if (e + j >= nc) L[j] = -INFINITY;  // masked tail
      float bm = fmaxf(fmaxf(fmaxf(L[0], L[1]), fmaxf(L[2], L[3])),
                       fmaxf(fmaxf(L[4], L[5]), fmaxf(L[6], L[7])));
      float mn = fmaxf(m, bm);
      float sc = __expf(m - mn);  // first batch: exp(-inf)=0
      float psum = 0.f, pdot = 0.f;
#pragma unroll
      for (int j = 0; j < 8; ++j) {
        float p = __expf(L[j] - mn);
        psum += p;
        pdot = fmaf(p, xv[j], pdot);
      }
      s = fmaf(s, sc, psum);
      acc = fmaf(acc, sc, pdot);
      m = mn;
    }
  }
  out[(size_t)v * CH + lane] = acc / s + boc;
}

// last layer: C_out = 1. xl8[v] = x[v,:]@Wl8 + bl8 (wave per node)
__global__ void __launch_bounds__(256) k_transform8(
    const float* __restrict__ x, const float* __restrict__ Wl, const float* __restrict__ bl,
    const float* __restrict__ Wr, const float* __restrict__ br,
    float* __restrict__ xl8, float* __restrict__ xr8, int n) {
  int lane = threadIdx.x & 63;
  int v = (blockIdx.x * blockDim.x + threadIdx.x) >> 6;
  if (v >= n) return;
  float xv = x[(size_t)v * CH + lane];
  float a = xv * Wl[lane];
  float b = xv * Wr[lane];
#pragma unroll
  for (int off = 32; off > 0; off >>= 1) {
    a += __shfl_xor(a, off, 64);
    b += __shfl_xor(b, off, 64);
  }
  if (lane == 0) {
    xl8[v] = a + bl[0];
    xr8[v] = b + br[0];
  }
}

// last layer aggregation (scalar channel), lane-per-edge, fused mean pool
__global__ void __launch_bounds__(256) k_agg8_mean(
    const float* __restrict__ xl8, const float* __restrict__ xr8,
    const int* __restrict__ row_beg, const int* __restrict__ deg,
    const int2* __restrict__ csr,
    const float* __restrict__ We, const float* __restrict__ att, const float* __restrict__ bo,
    float* __restrict__ out, int n) {
  int lane = threadIdx.x & 63;
  int wid = threadIdx.x >> 6;
  float We0 = We[0], att0 = att[0], bo0 = bo[0];
  float inv_n = 1.0f / (float)n;
  float local = 0.f;
  int nwaves = gridDim.x * 4;
  for (int v = blockIdx.x * 4 + wid; v < n; v += nwaves) {
    float xrc = xr8[v];
    int beg = row_beg[v], dv = deg[v];
    float m = -INFINITY, s = 0.f, acc = 0.f;
    for (int chunk = 0; chunk < dv; chunk += 64) {
      int idx = chunk + lane;
      bool valid = idx < dv;
      int2 ed = valid ? csr[beg + idx] : make_int2(0, 0);
      float xlc = valid ? xl8[ed.x] : 0.f;
      float ee = fmaf(__int_as_float(ed.y), We0, xlc + xrc);
      float logit = valid ? (ee > 0.f ? ee : 0.2f * ee) * att0 : -INFINITY;
      float bm = logit;
#pragma unroll
      for (int off = 32; off > 0; off >>= 1) bm = fmaxf(bm, __shfl_xor(bm, off, 64));
      float mn = fmaxf(m, bm);
      float p = __expf(logit - mn);
      float pd = p * xlc;
#pragma unroll
      for (int off = 32; off > 0; off >>= 1) {
        p += __shfl_xor(p, off, 64);
        pd += __shfl_xor(pd, off, 64);
      }
      float sc = __expf(m - mn);
      s = fmaf(s, sc, p);
      acc = fmaf(acc, sc, pd);
      m = mn;
    }
    local += (acc / s + bo0) * inv_n;
  }
  __shared__ float sw[4];
  if (lane == 0) sw[wid] = local;
  __syncthreads();
  if (threadIdx.x == 0) atomicAdd(out, sw[0] + sw[1] + sw[2] + sw[3]);
}

// ---- host ---------------------------------------------------------------

extern "C" void kernel_launch(void* const* d_in, const int* in_sizes, int n_in,
                              void* d_out, int out_size, void* d_ws, size_t ws_size,
                              hipStream_t stream) {
  const float* features = (const float*)d_in[0];
  const int* edge_src = (const int*)d_in[1];
  const int* edge_dst = (const int*)d_in[2];
  const float* edge_w = (const float*)d_in[3];
  const int N = in_sizes[0] / CH;
  const int E = in_sizes[1];

  char* p = (char*)d_ws;
  auto take = [&](size_t bytes) {
    char* r = p;
    p += (bytes + 255) & ~(size_t)255;
    return r;
  };
  float* xA = (float*)take((size_t)N * CH * 4);
  float* xB = (float*)take((size_t)N * CH * 4);
  float* xl = (float*)take((size_t)N * CH * 4);
  float* xr = (float*)take((size_t)N * CH * 4);
  int2* csr = (int2*)take((size_t)(E + N) * 8);
  char* zero_region = take((size_t)N * 4 * 3 + 256);
  int* cnt = (int*)zero_region;
  float* wsum = (float*)(zero_region + (size_t)N * 4);
  int* cursor = (int*)(zero_region + (size_t)N * 8);
  int* total = (int*)(zero_region + (size_t)N * 12);
  float* loop_attr = (float*)take((size_t)N * 4);
  int* deg = (int*)take((size_t)N * 4);
  int* row_beg = (int*)take((size_t)N * 4);
  float* xl8 = (float*)take((size_t)N * 4);
  float* xr8 = (float*)take((size_t)N * 4);

  hipMemsetAsync(zero_region, 0, (size_t)N * 4 * 3 + 256, stream);
  hipMemsetAsync(d_out, 0, sizeof(float), stream);

  const int tb = 256;
  k_count<<<(E + tb - 1) / tb, tb, 0, stream>>>(edge_dst, edge_w, E, cnt, wsum);
  k_alloc<<<(N + tb - 1) / tb, tb, 0, stream>>>(cnt, wsum, loop_attr, deg, row_beg, total, N);
  k_scatter<<<(E + tb - 1) / tb, tb, 0, stream>>>(edge_src, edge_dst, edge_w, E, row_beg,
                                                  cursor, csr);
  k_selfloop<<<(N + tb - 1) / tb, tb, 0, stream>>>(N, row_beg, cursor, csr, loop_attr);

  // param pointers
  const float* Wl1 = (const float*)d_in[4];
  const float* bl1 = (const float*)d_in[5];
  const float* Wr1 = (const float*)d_in[6];
  const float* br1 = (const float*)d_in[7];
  const float* We1 = (const float*)d_in[8];
  const float* att1 = (const float*)d_in[9];
  const float* bo1 = (const float*)d_in[10];
  const float* Wlm = (const float*)d_in[11];
  const float* blm = (const float*)d_in[12];
  const float* Wrm = (const float*)d_in[13];
  const float* brm = (const float*)d_in[14];
  const float* Wem = (const float*)d_in[15];
  const float* attm = (const float*)d_in[16];
  const float* bom = (const float*)d_in[17];

  const int agg_grid = ((size_t)N * 64 + tb - 1) / tb;
  const float* x_cur = features;
  float* x_nxt = xA;
  float* x_spare = xB;
  // layers 1..7: transform (x_cur -> xl,xr) then aggregate (-> x_nxt)
  for (int layer = 0; layer < 7; ++layer) {
    const float *Wl, *bl, *Wr, *br, *We, *att, *bo;
    if (layer == 0) {
      Wl = Wl1; bl = bl1; Wr = Wr1; br = br1; We = We1; att = att1; bo = bo1;
    } else {
      int i = layer - 1;
      Wl = Wlm + (size_t)i * CH * CH;
      bl = blm + (size_t)i * CH;
      Wr = Wrm + (size_t)i * CH * CH;
      br = brm + (size_t)i * CH;
      We = Wem + (size_t)i * CH;
      att = attm + (size_t)i * CH;
      bo = bom + (size_t)i * CH;
    }
    k_transform<<<1024, 256, 0, stream>>>(x_cur, Wl, bl, Wr, br, xl, xr, N);
    k_aggregate<<<agg_grid, tb, 0, stream>>>(xl, xr, row_beg, deg, csr, We, att, bo, x_nxt, N);
    x_cur = x_nxt;
    float* t = x_nxt == xA ? xB : xA;
    x_spare = x_nxt;
    x_nxt = t;
    (void)x_spare;
  }
  // layer 8: 64->1 transform, aggregate + mean pool
  k_transform8<<<agg_grid, tb, 0, stream>>>(
      x_cur, (const float*)d_in[18], (const float*)d_in[19], (const float*)d_in[20],
      (const float*)d_in[21], xl8, xr8, N);
  k_agg8_mean<<<1024, 256, 0, stream>>>(xl8, xr8, row_beg, deg, csr, (const float*)d_in[22],
                                        (const float*)d_in[23], (const float*)d_in[24],
                                        (float*)d_out, N);
}